// Round 5
// baseline (7602.431 us; speedup 1.0000x reference)
//
#include <hip/hip_runtime.h>

typedef unsigned short u16;
typedef unsigned int u32;

#define DD 256

__device__ __forceinline__ float b2f(u16 u){
  union { u32 i; float f; } c; c.i = ((u32)u) << 16; return c.f;
}
// round-to-nearest-even f32 -> bf16 (finite inputs)
__device__ __forceinline__ u16 f2b(float f){
  union { float f; u32 i; } c; c.f = f;
  u32 b = c.i + 0x7FFFu + ((c.i >> 16) & 1u);
  return (u16)(b >> 16);
}

// keep the harness's expected symbol name alive
__global__ void NodeEncoder_72971494359603_kernel(){}

// ---------------- dtype probe ----------------
// Examines 256 u32 words of a float embedding array. If the data is bf16,
// each word's LOW u16 is itself a bf16 of ~N(0, 0.05): exponent field
// (bits 7-14) lands in [0x60, 0x7E] essentially always. If the data is f32,
// the low u16 is mantissa bits (~uniform): ~12% in-window. flag=1 -> bf16.
__global__ void probe_dtype(const u32* w, u32* flag){
  if (threadIdx.x == 0 && blockIdx.x == 0){
    int cnt = 0;
    for (int i = 0; i < 256; i++){
      u32 low = w[i] & 0xFFFFu;
      u32 e = (low >> 7) & 0xFFu;
      if (e >= 0x60u && e <= 0x7Eu) cnt++;
    }
    *flag = (cnt >= 192) ? 1u : 0u;
  }
}

// convert a float input (bf16 or f32 per flag) into a bf16 working copy
__global__ void cvt_in(const void* src, u16* dst, int n, const u32* flag){
  int i = blockIdx.x * 256 + threadIdx.x;
  if (i < n){
    if (*flag){
      dst[i] = ((const u16*)src)[i];
    } else {
      dst[i] = f2b(((const float*)src)[i]);
    }
  }
}

// write staged bf16 result to d_out in the output dtype per flag
__global__ void store_out(const u16* h, void* dout, int n, const u32* flag){
  int i = blockIdx.x * 256 + threadIdx.x;
  if (i < n){
    if (*flag){
      ((u16*)dout)[i] = h[i];
    } else {
      ((float*)dout)[i] = b2f(h[i]);
    }
  }
}

// ---------------- utility ----------------
__global__ void zero_int(int* p, int n){
  int i = blockIdx.x * 256 + threadIdx.x;
  if (i < n) p[i] = 0;
}

// TBL[(l*18 + a*3 + b)*256 + j] = ee1[l][a][j] + ee2[l][b][j]   (f32)
__global__ void build_table(const u16* ee1, const u16* ee2, float* TBL){
  int b = blockIdx.x;               // 0..89
  int l = b / 18, c = b % 18, a = c / 3, bb = c % 3;
  int j = threadIdx.x;
  TBL[b * DD + j] = b2f(ee1[(l * 6 + a) * DD + j]) + b2f(ee2[(l * 3 + bb) * DD + j]);
}

// ---------------- CSR build ----------------
__global__ void hist_kernel(const int* dst, int* counts, int E){
  int e = blockIdx.x * 256 + threadIdx.x;
  if (e < E) atomicAdd(&counts[dst[e]], 1);
}

__global__ void scan_sums(const int* counts, int* bsum, int N){
  __shared__ int red[256];
  int tid = threadIdx.x;
  int base = blockIdx.x * 1024;
  int s = 0;
  for (int i = tid; i < 1024; i += 256){
    int g = base + i;
    if (g < N) s += counts[g];
  }
  red[tid] = s;
  __syncthreads();
  for (int off = 128; off > 0; off >>= 1){
    if (tid < off) red[tid] += red[tid + off];
    __syncthreads();
  }
  if (tid == 0) bsum[blockIdx.x] = red[0];
}

__global__ void scan_top(int* bsum, int nb){
  if (threadIdx.x == 0 && blockIdx.x == 0){
    int acc = 0;
    for (int i = 0; i < nb; i++){ int t = bsum[i]; bsum[i] = acc; acc += t; }
  }
}

__global__ void scan_block(const int* counts, const int* bsum,
                           int* offsets, int* cursor, int N){
  __shared__ int tsum[256];
  int b = blockIdx.x;
  int tid = threadIdx.x;
  int base = b * 1024;
  int v0, v1, v2, v3;
  int g = base + tid * 4;
  v0 = (g + 0 < N) ? counts[g + 0] : 0;
  v1 = (g + 1 < N) ? counts[g + 1] : 0;
  v2 = (g + 2 < N) ? counts[g + 2] : 0;
  v3 = (g + 3 < N) ? counts[g + 3] : 0;
  tsum[tid] = v0 + v1 + v2 + v3;
  __syncthreads();
  for (int off = 1; off < 256; off <<= 1){
    int t = (tid >= off) ? tsum[tid - off] : 0;
    __syncthreads();
    tsum[tid] += t;
    __syncthreads();
  }
  int excl = (tid == 0 ? 0 : tsum[tid - 1]) + bsum[b];
  if (g + 0 < N){ offsets[g + 0] = excl; cursor[g + 0] = excl; } excl += v0;
  if (g + 1 < N){ offsets[g + 1] = excl; cursor[g + 1] = excl; } excl += v1;
  if (g + 2 < N){ offsets[g + 2] = excl; cursor[g + 2] = excl; } excl += v2;
  if (g + 3 < N){ offsets[g + 3] = excl; cursor[g + 3] = excl; }
}

// payload[pos] = src | ((ea0*3+ea1) << 17)
__global__ void fill_csr(const int* ei, const int* ea, int* cursor,
                         int* payload, int E){
  int e = blockIdx.x * 256 + threadIdx.x;
  if (e < E){
    int d = ei[E + e];
    int pos = atomicAdd(&cursor[d], 1);
    int a = ea[2 * e], bb = ea[2 * e + 1];
    payload[pos] = ei[e] | ((a * 3 + bb) << 17);
  }
}

// ---------------- node embedding ----------------
__global__ void node_embed(const int* x, const u16* xe1, const u16* xe2,
                           u16* out, int N){
  int idx = blockIdx.x * 256 + threadIdx.x;
  if (idx < N * DD){
    int n = idx >> 8, j = idx & 255;
    int x0 = x[2 * n], x1 = x[2 * n + 1];
    out[idx] = f2b(b2f(xe1[x0 * DD + j]) + b2f(xe2[x1 * DD + j]));
  }
}

// ---------------- aggregation (CSR gather-sum) ----------------
// wave-per-node, each of 64 lanes handles 4 columns scalar.
__global__ void aggregate(const u16* feat, const float* TBL,
                          const int* offsets, const int* counts,
                          const int* payload, u16* agg, int N){
  __shared__ float T[18 * DD];
  int tid = threadIdx.x;
  for (int i = tid; i < 18 * DD; i += 256) T[i] = TBL[i];
  __syncthreads();
  int wave = tid >> 6, lane = tid & 63;
  int c4 = lane * 4;
  int n0 = blockIdx.x * 32 + wave * 8;
  for (int u = 0; u < 8; u++){
    int n = n0 + u;
    if (n >= N) return;
    const u16* selfp = feat + (size_t)n * DD + c4;
    float a0 = b2f(selfp[0]) + T[12 * DD + c4 + 0];  // self-loop: (4,0) -> idx 12
    float a1 = b2f(selfp[1]) + T[12 * DD + c4 + 1];
    float a2 = b2f(selfp[2]) + T[12 * DD + c4 + 2];
    float a3 = b2f(selfp[3]) + T[12 * DD + c4 + 3];
    int e0 = offsets[n], cnt = counts[n];
    for (int e = e0; e < e0 + cnt; e++){
      int pl = payload[e];
      int src = pl & 0x1FFFF;
      int idx = pl >> 17;
      const u16* rp = feat + (size_t)src * DD + c4;
      const float* tp = T + idx * DD + c4;
      a0 += b2f(rp[0]) + tp[0];
      a1 += b2f(rp[1]) + tp[1];
      a2 += b2f(rp[2]) + tp[2];
      a3 += b2f(rp[3]) + tp[3];
    }
    u16* op = agg + (size_t)n * DD + c4;
    op[0] = f2b(a0); op[1] = f2b(a1); op[2] = f2b(a2); op[3] = f2b(a3);
  }
}

// ---- f32 SGEMM: C[M,Nc] = A[M,K] @ W[K,Nc] + bias, optional relu ----
// 64x64 tile, 256 threads, 4x4 per thread, K-tile 32. All scalar.
__global__ void gemm_fb(const u16* A, const u16* W, const u16* bias,
                        u16* C, int M, int K, int Nc, int relu){
  __shared__ float As[64][33];
  __shared__ float Bs[32][65];
  int tid = threadIdx.x;
  int row0 = blockIdx.x * 64, col0 = blockIdx.y * 64;
  int tr = tid >> 4, tc = tid & 15;
  float acc00=0.f, acc01=0.f, acc02=0.f, acc03=0.f;
  float acc10=0.f, acc11=0.f, acc12=0.f, acc13=0.f;
  float acc20=0.f, acc21=0.f, acc22=0.f, acc23=0.f;
  float acc30=0.f, acc31=0.f, acc32=0.f, acc33=0.f;
  for (int k0 = 0; k0 < K; k0 += 32){
    for (int p = 0; p < 8; p++){
      int lin = p * 256 + tid;      // 0..2047
      int r = lin >> 5, kk = lin & 31;
      int gr = row0 + r;
      As[r][kk] = (gr < M) ? b2f(A[(size_t)gr * K + k0 + kk]) : 0.0f;
    }
    for (int p = 0; p < 8; p++){
      int lin = p * 256 + tid;
      int kk = lin >> 6, c = lin & 63;
      Bs[kk][c] = b2f(W[(size_t)(k0 + kk) * Nc + col0 + c]);
    }
    __syncthreads();
    for (int kk = 0; kk < 32; kk++){
      float a0 = As[tr * 4 + 0][kk];
      float a1 = As[tr * 4 + 1][kk];
      float a2 = As[tr * 4 + 2][kk];
      float a3 = As[tr * 4 + 3][kk];
      float b0 = Bs[kk][tc * 4 + 0];
      float b1 = Bs[kk][tc * 4 + 1];
      float b2 = Bs[kk][tc * 4 + 2];
      float b3 = Bs[kk][tc * 4 + 3];
      acc00 += a0 * b0; acc01 += a0 * b1; acc02 += a0 * b2; acc03 += a0 * b3;
      acc10 += a1 * b0; acc11 += a1 * b1; acc12 += a1 * b2; acc13 += a1 * b3;
      acc20 += a2 * b0; acc21 += a2 * b1; acc22 += a2 * b2; acc23 += a2 * b3;
      acc30 += a3 * b0; acc31 += a3 * b1; acc32 += a3 * b2; acc33 += a3 * b3;
    }
    __syncthreads();
  }
  float accs[4][4];
  accs[0][0]=acc00; accs[0][1]=acc01; accs[0][2]=acc02; accs[0][3]=acc03;
  accs[1][0]=acc10; accs[1][1]=acc11; accs[1][2]=acc12; accs[1][3]=acc13;
  accs[2][0]=acc20; accs[2][1]=acc21; accs[2][2]=acc22; accs[2][3]=acc23;
  accs[3][0]=acc30; accs[3][1]=acc31; accs[3][2]=acc32; accs[3][3]=acc33;
  for (int i = 0; i < 4; i++){
    int row = row0 + tr * 4 + i;
    if (row >= M) continue;
    for (int j = 0; j < 4; j++){
      int col = col0 + tc * 4 + j;
      float v = accs[i][j] + b2f(bias[col]);
      if (relu && v < 0.0f) v = 0.0f;
      C[(size_t)row * Nc + col] = f2b(v);
    }
  }
}

// ---------------- BatchNorm (no float atomics) ----------------
__global__ void bn_stats(const u16* h, float* partial, int N, int rpb){
  int j = threadIdx.x;
  int b = blockIdx.x;
  int r0 = b * rpb;
  int r1 = r0 + rpb; if (r1 > N) r1 = N;
  float s = 0.f, s2 = 0.f;
  for (int r = r0; r < r1; r++){
    float v = b2f(h[(size_t)r * DD + j]);
    s += v; s2 += v * v;
  }
  partial[(size_t)b * DD + j] = s;
  partial[(size_t)(128 + b) * DD + j] = s2;
}

__global__ void bn_reduce(const float* partial, float* sums){
  int j = threadIdx.x;
  int which = blockIdx.x;      // 0 = sum, 1 = sumsq
  float s = 0.f;
  for (int i = 0; i < 128; i++)
    s += partial[(size_t)(which * 128 + i) * DD + j];
  sums[which * DD + j] = s;
}

__global__ void bn_apply(const u16* h, const float* sums,
                         const u16* gamma, const u16* beta,
                         u16* out, int N, int rpb, float invN){
  int j = threadIdx.x;
  float mean = sums[j] * invN;
  float var = sums[DD + j] * invN - mean * mean;
  if (var < 0.f) var = 0.f;
  float sc = rsqrtf(var + 1e-5f) * b2f(gamma[j]);
  float sh = b2f(beta[j]) - mean * sc;
  int r0 = blockIdx.x * rpb;
  int r1 = r0 + rpb; if (r1 > N) r1 = N;
  for (int r = r0; r < r1; r++){
    float v = b2f(h[(size_t)r * DD + j]) * sc + sh;
    if (v < 0.0f) v = 0.0f;
    out[(size_t)r * DD + j] = f2b(v);
  }
}

// ---------------- host ----------------
extern "C" void kernel_launch(void* const* d_in, const int* in_sizes, int n_in,
                              void* d_out, int out_size, void* d_ws, size_t ws_size,
                              hipStream_t stream){
  (void)n_in; (void)out_size;
  const int* x    = (const int*)d_in[0];
  const int* ei   = (const int*)d_in[1];
  const int* ea   = (const int*)d_in[2];
  const void* xe1 = d_in[3];
  const void* xe2 = d_in[4];
  const void* ee1 = d_in[5];
  const void* ee2 = d_in[6];
  const void* W1  = d_in[7];
  const void* b1  = d_in[8];
  const void* W2  = d_in[9];
  const void* b2  = d_in[10];
  const void* gam = d_in[11];
  const void* bet = d_in[12];

  int N = in_sizes[0] / 2;
  int E = in_sizes[1] / 2;
  int NB = (N + 1023) / 1024;
  const int L = 5;

  // manual workspace carve (256B aligned)
  char* base = (char*)d_ws;
  size_t off = 0;
  u32* flag    = (u32*)(base + off);   off += 256;
  float* TBL   = (float*)(base + off); off += ((size_t)L * 18 * DD * 4 + 255) & ~(size_t)255;
  int* counts  = (int*)(base + off);   off += ((size_t)N * 4 + 255) & ~(size_t)255;
  int* offsets = (int*)(base + off);   off += ((size_t)N * 4 + 255) & ~(size_t)255;
  int* cursor  = (int*)(base + off);   off += ((size_t)N * 4 + 255) & ~(size_t)255;
  int* bsum    = (int*)(base + off);   off += ((size_t)NB * 4 + 255) & ~(size_t)255;
  int* payload = (int*)(base + off);   off += ((size_t)E * 4 + 255) & ~(size_t)255;
  float* part  = (float*)(base + off); off += ((size_t)256 * DD * 4 + 255) & ~(size_t)255;
  float* sums  = (float*)(base + off); off += ((size_t)2 * DD * 4 + 255) & ~(size_t)255;
  // bf16 working copies of float inputs
  u16* wx1  = (u16*)(base + off); off += ((size_t)120 * DD * 2 + 255) & ~(size_t)255;
  u16* wx2  = (u16*)(base + off); off += ((size_t)3 * DD * 2 + 255) & ~(size_t)255;
  u16* wee1 = (u16*)(base + off); off += ((size_t)L * 6 * DD * 2 + 255) & ~(size_t)255;
  u16* wee2 = (u16*)(base + off); off += ((size_t)L * 3 * DD * 2 + 255) & ~(size_t)255;
  u16* wW1  = (u16*)(base + off); off += ((size_t)L * DD * 2 * DD * 2 + 255) & ~(size_t)255;
  u16* wb1  = (u16*)(base + off); off += ((size_t)L * 2 * DD * 2 + 255) & ~(size_t)255;
  u16* wW2  = (u16*)(base + off); off += ((size_t)L * 2 * DD * DD * 2 + 255) & ~(size_t)255;
  u16* wb2  = (u16*)(base + off); off += ((size_t)L * DD * 2 + 255) & ~(size_t)255;
  u16* wgam = (u16*)(base + off); off += ((size_t)(L - 1) * DD * 2 + 255) & ~(size_t)255;
  u16* wbet = (u16*)(base + off); off += ((size_t)(L - 1) * DD * 2 + 255) & ~(size_t)255;
  // big feature buffers (bf16)
  u16* feat = (u16*)(base + off); off += ((size_t)N * DD * 2 + 255) & ~(size_t)255;
  u16* agg  = (u16*)(base + off); off += ((size_t)N * DD * 2 + 255) & ~(size_t)255;
  // mid chunk sized to fit remaining workspace
  size_t remain = (ws_size > off + 4096) ? (ws_size - off - 4096) : 0;
  long long chv = (long long)(remain / ((size_t)2 * DD * 2));  // bytes per mid row = 512*2
  int CH = (int)(chv < 2048 ? 2048 : (chv > 32768 ? 32768 : chv));
  CH &= ~63;
  if (CH > N) CH = (N + 63) & ~63;
  u16* mid = (u16*)(base + off); off += (size_t)CH * 2 * DD * 2;

  // dtype probe + input conversion to bf16 working copies
  probe_dtype<<<1, 64, 0, stream>>>((const u32*)xe1, flag);
  cvt_in<<<(120 * DD + 255) / 256, 256, 0, stream>>>(xe1, wx1, 120 * DD, flag);
  cvt_in<<<(3 * DD + 255) / 256, 256, 0, stream>>>(xe2, wx2, 3 * DD, flag);
  cvt_in<<<(L * 6 * DD + 255) / 256, 256, 0, stream>>>(ee1, wee1, L * 6 * DD, flag);
  cvt_in<<<(L * 3 * DD + 255) / 256, 256, 0, stream>>>(ee2, wee2, L * 3 * DD, flag);
  cvt_in<<<(L * DD * 2 * DD + 255) / 256, 256, 0, stream>>>(W1, wW1, L * DD * 2 * DD, flag);
  cvt_in<<<(L * 2 * DD + 255) / 256, 256, 0, stream>>>(b1, wb1, L * 2 * DD, flag);
  cvt_in<<<(L * 2 * DD * DD + 255) / 256, 256, 0, stream>>>(W2, wW2, L * 2 * DD * DD, flag);
  cvt_in<<<(L * DD + 255) / 256, 256, 0, stream>>>(b2, wb2, L * DD, flag);
  cvt_in<<<((L - 1) * DD + 255) / 256, 256, 0, stream>>>(gam, wgam, (L - 1) * DD, flag);
  cvt_in<<<((L - 1) * DD + 255) / 256, 256, 0, stream>>>(bet, wbet, (L - 1) * DD, flag);

  // one-time per call: tables, CSR
  build_table<<<90, 256, 0, stream>>>(wee1, wee2, TBL);
  zero_int<<<(N + 255) / 256, 256, 0, stream>>>(counts, N);
  hist_kernel<<<(E + 255) / 256, 256, 0, stream>>>(ei + E, counts, E);
  scan_sums<<<NB, 256, 0, stream>>>(counts, bsum, N);
  scan_top<<<1, 64, 0, stream>>>(bsum, NB);
  scan_block<<<NB, 256, 0, stream>>>(counts, bsum, offsets, cursor, N);
  fill_csr<<<(E + 255) / 256, 256, 0, stream>>>(ei, ea, cursor, payload, E);

  // initial node features
  node_embed<<<(N * DD + 255) / 256, 256, 0, stream>>>(x, wx1, wx2, feat, N);

  int rpb_s = (N + 127) / 128;   // bn_stats rows/block (128 blocks)
  int rpb_a = (N + 511) / 512;   // bn_apply rows/block (512 blocks)
  float invN = 1.0f / (float)N;

  for (int l = 0; l < L; l++){
    aggregate<<<(N + 31) / 32, 256, 0, stream>>>(
        feat, TBL + (size_t)l * 18 * DD, offsets, counts, payload, agg, N);

    // chunked MLP: rows [r0, r0+CH)
    for (int r0 = 0; r0 < N; r0 += CH){
      int rows = N - r0; if (rows > CH) rows = CH;
      int gm = (rows + 63) / 64;
      // GEMM1: [rows,256] x [256,512] + b1, relu -> mid
      gemm_fb<<<dim3(gm, 8), 256, 0, stream>>>(
          agg + (size_t)r0 * DD, wW1 + (size_t)l * DD * 2 * DD,
          wb1 + (size_t)l * 2 * DD, mid, rows, DD, 2 * DD, 1);
      // GEMM2: [rows,512] x [512,256] + b2 -> h (into agg rows)
      gemm_fb<<<dim3(gm, 4), 256, 0, stream>>>(
          mid, wW2 + (size_t)l * 2 * DD * DD,
          wb2 + (size_t)l * DD, agg + (size_t)r0 * DD, rows, 2 * DD, DD, 0);
    }

    if (l < L - 1){
      bn_stats<<<128, 256, 0, stream>>>(agg, part, N, rpb_s);
      bn_reduce<<<2, 256, 0, stream>>>(part, sums);
      bn_apply<<<512, 256, 0, stream>>>(agg, sums, wgam + (size_t)l * DD,
                                        wbet + (size_t)l * DD, feat, N, rpb_a, invN);
    }
  }

  // final h is in agg; write to d_out in the proper dtype
  store_out<<<(N * DD + 255) / 256, 256, 0, stream>>>(agg, d_out, N * DD, flag);
}